// Round 6
// baseline (613.820 us; speedup 1.0000x reference)
//
#include <hip/hip_runtime.h>
#include <cstddef>
#include <cstdint>

#define BATCH_N 32768
#define OUT_DIM 10
#define HS 524288   // split-half offset in floats (8 matrices x 65536)

typedef unsigned short u16;
typedef __attribute__((ext_vector_type(8))) _Float16 half8;
typedef __attribute__((ext_vector_type(4))) float f32x4;

__device__ __forceinline__ u16 f2h(float v) {
    _Float16 h = (_Float16)v;                 // RTN
    return __builtin_bit_cast(u16, h);
}
__device__ __forceinline__ float h2f(u16 h) {
    return (float)__builtin_bit_cast(_Float16, h);
}
__device__ __forceinline__ float tanh_fast(float x) {
    float e = __expf(2.f * x);        // inf -> 1, 0 -> -1 : robust
    return 1.f - 2.f / (e + 1.f);
}

// ============================================================================
// MEGA-FUSED NETWORK KERNEL (R12: R10's row-split layer loop, spill-fixed).
// Evidence: __launch_bounds__(1024,4) capped the allocator at 64 VGPRs
// (VGPR_Count=64 in R8 AND R10); R10's ~116-live-reg loop spilled 138MB to
// scratch.  __launch_bounds__(1024) alone -> launchability cap 128 VGPR.
// Layer loop: 16 waves = 2 row-halves (g) x 8 col-groups (wc); each wave
// reads HALF the A-panel (halves the LDS-read bottleneck: 24.6K->12.3K
// cy/CU/layer) and owns 64 cols (z0/z1 at u, u+16): acc[4][4] + B[2][4].
// State [128 x 512] f16 in LDS; A-fragment layout: (m,k) ->
// state[(k>>5)*4096 + (m>>4)*512 + (((k>>3)&3)*16 + (m&15))*8 + (k&7)].
// Weights Wc[layer][c][512] f16, c<256 -> z0 row u=c, c>=256 -> z1 row u=c-256.
// ============================================================================
__global__ __launch_bounds__(1024)
void meganet(const float* __restrict__ X,
             const u16* __restrict__ Wi,        // [256 u][800 k] f16
             const float* __restrict__ b_in,
             const u16* __restrict__ Wc,        // [8][512 c][512 k] f16
             const float* __restrict__ cc,      // [8][512]: [0..255]=c0, [256..511]=c1
             const float* __restrict__ Wo, const float* __restrict__ bo,
             float* __restrict__ out)
{
    __shared__ u16 state[65536];     // 128 KB
    __shared__ float aux[4096];      // 16 KB: x double-buffer, later W_out copy
    const int t = threadIdx.x;
    const int wave = t >> 6, lane = t & 63;
    const int fl = lane & 15, kq = lane >> 4;
    const int b0 = blockIdx.x * 128;

    // ---------------- input stage: v0 = x @ W_in + b_in (K=784, pad 800) ----
    f32x4 ai[8];
#pragma unroll
    for (int a = 0; a < 8; ++a) ai[a] = (f32x4){0.f, 0.f, 0.f, 0.f};

    const u16* bpIn = Wi + (size_t)(wave * 16 + fl) * 800 + kq * 8;

    u16* xbuf = (u16*)aux;           // 2 x 4096 u16 chunk buffers
    const int xr = t >> 3;           // row 0..127
    const int xk = (t & 7) * 4;      // 0..28 step 4
    const size_t xrow = (size_t)(b0 + xr) * 784;
    const int xoff = (xr >> 4) * 512 + ((xk >> 3) * 16 + (xr & 15)) * 8 + (xk & 7);

    half8 IB[2];
    float4 xa;
    {   // prologue: chunk0 -> buf0
        float4 x0 = *(const float4*)(X + xrow + xk);
        ushort4 h;
        h.x = f2h(x0.x); h.y = f2h(x0.y); h.z = f2h(x0.z); h.w = f2h(x0.w);
        *(ushort4*)&xbuf[xoff] = h;
        xa = *(const float4*)(X + xrow + 32 + xk);     // chunk 1
        IB[0] = *(const half8*)(bpIn);                 // chunk 0 weights
    }

#pragma unroll
    for (int ki = 0; ki < 25; ++ki) {
        const int cur = ki & 1, nxt = cur ^ 1;
        __syncthreads();                 // buf[cur] ready; buf[nxt] reads done
        if (ki < 24) {                   // stage chunk ki+1 into buf[nxt]
            ushort4 h;
            h.x = f2h(xa.x); h.y = f2h(xa.y); h.z = f2h(xa.z); h.w = f2h(xa.w);
            *(ushort4*)&xbuf[nxt * 4096 + xoff] = h;
            if (ki < 23) {               // load chunk ki+2 (depth-2)
                const int gk = (ki + 2) * 32 + xk;
                const int ga = (gk <= 780) ? gk : 780;   // Wi packs 0 for k>=784
                xa = *(const float4*)(X + xrow + ga);
            }
            IB[nxt] = *(const half8*)(bpIn + (ki + 1) * 32);
        }
        const u16* rb = xbuf + cur * 4096;
#pragma unroll
        for (int mt = 0; mt < 8; ++mt) {
            half8 af = *(const half8*)&rb[mt * 512 + lane * 8];
            ai[mt] = __builtin_amdgcn_mfma_f32_16x16x32_f16(af, IB[cur], ai[mt], 0, 0, 0);
        }
    }

    // layer mapping: g = row half (0: rows 0..63, 1: 64..127), wc = col group
    const int g = wave >> 3, wc = wave & 7;
    // layer-0 ks=0 weight prefetch (4 cols: z0 u, z0 u+16, z1 u, z1 u+16)
    const u16* p00 = Wc + (size_t)(wc * 32 + fl) * 512 + kq * 8;
    const u16* p01 = p00 + 8192;       // +16 cols
    const u16* p10 = p00 + 131072;     // z1 (+256 cols)
    const u16* p11 = p01 + 131072;
    half8 B[2][4];
    B[0][0] = *(const half8*)p00;
    B[0][1] = *(const half8*)p01;
    B[0][2] = *(const half8*)p10;
    B[0][3] = *(const half8*)p11;

    // input epilogue: state v0 (k=u), w = 2*tanh(v0) (k=256+u)
    {
        const float bi = b_in[wave * 16 + fl];
        const int u = wave * 16 + fl;
        const int slab = u >> 5;
        const int cbase = ((u >> 3) & 3) * 128 + (u & 7);
#pragma unroll
        for (int mt = 0; mt < 8; ++mt) {
#pragma unroll
            for (int r = 0; r < 4; ++r) {
                float v = ai[mt][r] + bi;
                float w = 2.f * tanh_fast(v);
                const int base = mt * 512 + (kq * 4 + r) * 8 + cbase;
                state[slab * 4096 + base] = f2h(v);
                state[(8 + slab) * 4096 + base] = f2h(w);
            }
        }
    }

    // ---------------- 8 implicit layers ----------------
    for (int L = 0; L < 8; ++L) {
        float ccv[4];
        ccv[0] = cc[L * 512 + wc * 32 + fl];
        ccv[1] = cc[L * 512 + wc * 32 + 16 + fl];
        ccv[2] = cc[L * 512 + 256 + wc * 32 + fl];
        ccv[3] = cc[L * 512 + 256 + wc * 32 + 16 + fl];
        f32x4 acc[4][4];
#pragma unroll
        for (int a = 0; a < 4; ++a)
#pragma unroll
            for (int b = 0; b < 4; ++b) acc[a][b] = (f32x4){0.f, 0.f, 0.f, 0.f};
        __syncthreads();   // state ready
#pragma unroll
        for (int ks = 0; ks < 16; ++ks) {
            const int cur = ks & 1, nxt = cur ^ 1;
            if (ks < 15) {             // prefetch next K-step (4 x 16B)
                B[nxt][0] = *(const half8*)(p00 + (ks + 1) * 32);
                B[nxt][1] = *(const half8*)(p01 + (ks + 1) * 32);
                B[nxt][2] = *(const half8*)(p10 + (ks + 1) * 32);
                B[nxt][3] = *(const half8*)(p11 + (ks + 1) * 32);
            } else {                   // prefetch next layer's ks=0 across epilogue
                p00 += 262144; p01 += 262144; p10 += 262144; p11 += 262144;
                if (L < 7) {
                    B[nxt][0] = *(const half8*)p00;
                    B[nxt][1] = *(const half8*)p01;
                    B[nxt][2] = *(const half8*)p10;
                    B[nxt][3] = *(const half8*)p11;
                }
            }
#pragma unroll
            for (int mt = 0; mt < 4; ++mt) {
                half8 af = *(const half8*)&state[ks * 4096 + (g * 4 + mt) * 512 + lane * 8];
                acc[mt][0] = __builtin_amdgcn_mfma_f32_16x16x32_f16(af, B[cur][0], acc[mt][0], 0, 0, 0);
                acc[mt][1] = __builtin_amdgcn_mfma_f32_16x16x32_f16(af, B[cur][1], acc[mt][1], 0, 0, 0);
                acc[mt][2] = __builtin_amdgcn_mfma_f32_16x16x32_f16(af, B[cur][2], acc[mt][2], 0, 0, 0);
                acc[mt][3] = __builtin_amdgcn_mfma_f32_16x16x32_f16(af, B[cur][3], acc[mt][3], 0, 0, 0);
            }
        }
        __syncthreads();   // all state reads done; safe to overwrite
        // epilogue: thread owns z0/z1 at u and u+16 on its row half (no shfl)
#pragma unroll
        for (int nt2 = 0; nt2 < 2; ++nt2) {
            const int u = wc * 32 + nt2 * 16 + fl;
            const int slab = u >> 5;
            const int cbase = ((u >> 3) & 3) * 128 + (u & 7);
#pragma unroll
            for (int mt = 0; mt < 4; ++mt) {
                const int rb = (g * 4 + mt) * 512;
#pragma unroll
                for (int r = 0; r < 4; ++r) {
                    float z0 = acc[mt][nt2][r] + ccv[nt2];
                    float z1 = acc[mt][2 + nt2][r] + ccv[2 + nt2];
                    float tv = tanh_fast(z0);
                    const int base = rb + (kq * 4 + r) * 8 + cbase;
                    state[slab * 4096 + base] = f2h(z0);
                    state[(8 + slab) * 4096 + base] = f2h(z1 + tv);
                }
            }
        }
    }

    // ---------------- output stage: out = v0 @ W_out + b_out ----------------
    __syncthreads();
    for (int i = t; i < 2560; i += 1024) aux[i] = Wo[i];
    __syncthreads();
    {
        const int m = t >> 3;        // 0..127
        const int o = t & 7;
        float s = bo[o];
        for (int kb = 0; kb < 256; kb += 8) {
            const int off = (kb >> 5) * 4096 + (m >> 4) * 512 +
                            (((kb >> 3) & 3) * 16 + (m & 15)) * 8;
            ushort4 h0 = *(const ushort4*)&state[off];
            ushort4 h1 = *(const ushort4*)&state[off + 4];
            s += h2f(h0.x) * aux[(kb + 0) * 10 + o] + h2f(h0.y) * aux[(kb + 1) * 10 + o]
               + h2f(h0.z) * aux[(kb + 2) * 10 + o] + h2f(h0.w) * aux[(kb + 3) * 10 + o]
               + h2f(h1.x) * aux[(kb + 4) * 10 + o] + h2f(h1.y) * aux[(kb + 5) * 10 + o]
               + h2f(h1.z) * aux[(kb + 6) * 10 + o] + h2f(h1.w) * aux[(kb + 7) * 10 + o];
        }
        out[(size_t)(b0 + m) * 10 + o] = s;
    }
    if (t < 256) {
        const int m = t >> 1;
        const int o = 8 + (t & 1);
        float s = bo[o];
        for (int kb = 0; kb < 256; kb += 8) {
            const int off = (kb >> 5) * 4096 + (m >> 4) * 512 +
                            (((kb >> 3) & 3) * 16 + (m & 15)) * 8;
            ushort4 h0 = *(const ushort4*)&state[off];
            ushort4 h1 = *(const ushort4*)&state[off + 4];
            s += h2f(h0.x) * aux[(kb + 0) * 10 + o] + h2f(h0.y) * aux[(kb + 1) * 10 + o]
               + h2f(h0.z) * aux[(kb + 2) * 10 + o] + h2f(h0.w) * aux[(kb + 3) * 10 + o]
               + h2f(h1.x) * aux[(kb + 4) * 10 + o] + h2f(h1.y) * aux[(kb + 5) * 10 + o]
               + h2f(h1.z) * aux[(kb + 6) * 10 + o] + h2f(h1.w) * aux[(kb + 7) * 10 + o];
        }
        out[(size_t)(b0 + m) * 10 + o] = s;
    }
}

// ============================================================================
// R12 prep: 2 NS iterations (Gershgorin seed rho0~0.1 -> rho2~1e-4, 5x below
// f16 pack quantization), merged dispatches: k1 -> Y1 -> X1 -> Y2 -> M ->
// {P,Q} -> {R,cc} -> pack.  K-split x2; split results summed by consumers.
// ============================================================================

template<bool S>
__device__ __forceinline__ float4 ld4(const float* __restrict__ p, size_t idx) {
    float4 v = *(const float4*)(p + idx);
    if constexpr (S) {
        float4 w = *(const float4*)(p + idx + HS);
        v.x += w.x; v.y += w.y; v.z += w.z; v.w += w.w;
    }
    return v;
}

// One 64x64 tile, K-range [kh*KLEN, kh*KLEN+KLEN). acc = A^T B over that range.
// EPI: 0 D=acc | 1 D=acc+2I & Gershgorin rowsum->scr (KLEN=256 only)
//      2 D=2E-acc | 3 D=ca*E+cb*acc | 4 D=2ca*I+2cb*E-ca*E2-cb*acc
// (EPI 2/3/4 emit the constant/E terms only on the kh==0 half.)
template<int EPI, int KLEN, bool AS, bool BS, bool ES>
__device__ __forceinline__ void gemm_body(float* __restrict__ D,
        const float* __restrict__ A, const float* __restrict__ Bm,
        const float* __restrict__ E, const float* __restrict__ E2,
        const float* __restrict__ scr_r, float* __restrict__ scr_w,
        int i, int u0, int v0, int kh)
{
    __shared__ float As[16][64];
    __shared__ float Bs[16][64];
    const size_t off = (size_t)i * 65536;
    const int t  = threadIdx.x;
    const int tx = t & 15, ty = t >> 4;
    const int lk = t >> 4, lv = (t & 15) << 2;

    float ca = 0.f, cb = 0.f;
    if (EPI == 3 || EPI == 4) {        // NS seed coefficients from rowsums
        float* red = &As[0][0];
        red[t] = scr_r[i * 256 + t];
        __syncthreads();
        for (int o = 128; o >= 1; o >>= 1) {
            if (t < o) red[t] = fmaxf(red[t], red[t + o]);
            __syncthreads();
        }
        const float bt_ = red[0];                  // >= lambda_max; lambda_min >= 2
        const float r = (2.f + bt_) * (2.f + bt_) / (8.f * bt_);
        const float e = (r - 1.f) / (r + 1.f);
        cb = -(1.f - e) / (2.f * bt_);
        ca = -cb * (2.f + bt_);
        __syncthreads();
    }

    const int kb = kh * KLEN;
    float acc[4][4];
#pragma unroll
    for (int m = 0; m < 4; ++m)
#pragma unroll
        for (int n = 0; n < 4; ++n) acc[m][n] = 0.f;

    float4 an = ld4<AS>(A, off + (size_t)(kb + lk) * 256 + u0 + lv);
    float4 bn = ld4<BS>(Bm, off + (size_t)(kb + lk) * 256 + v0 + lv);

    for (int k0 = 0; k0 < KLEN; k0 += 16) {
        if (k0) __syncthreads();
        *(float4*)&As[lk][lv] = an;
        *(float4*)&Bs[lk][lv] = bn;
        if (k0 < KLEN - 16) {
            an = ld4<AS>(A, off + (size_t)(kb + k0 + 16 + lk) * 256 + u0 + lv);
            bn = ld4<BS>(Bm, off + (size_t)(kb + k0 + 16 + lk) * 256 + v0 + lv);
        }
        __syncthreads();
#pragma unroll
        for (int kk = 0; kk < 16; ++kk) {
            float af[4], bf[4];
            *(float4*)&af[0] = *(const float4*)&As[kk][ty * 4];
            *(float4*)&bf[0] = *(const float4*)&Bs[kk][tx * 4];
#pragma unroll
            for (int m = 0; m < 4; ++m)
#pragma unroll
                for (int n = 0; n < 4; ++n) acc[m][n] += af[m] * bf[n];
        }
    }

    float* Dp = D + (size_t)kh * HS;   // split kernels write their half
#pragma unroll
    for (int m = 0; m < 4; ++m) {
        const int u = u0 + ty * 4 + m;
        const size_t idx = off + (size_t)u * 256 + v0 + tx * 4;
        float4 r; float* rf = &r.x;
        if (EPI == 0) {
#pragma unroll
            for (int n = 0; n < 4; ++n) rf[n] = acc[m][n];
        } else if (EPI == 1) {
#pragma unroll
            for (int n = 0; n < 4; ++n)
                rf[n] = acc[m][n] + ((u == v0 + tx * 4 + n) ? 2.f : 0.f);
        } else if (EPI == 2) {
            if (kh == 0) {
                float4 e4 = ld4<ES>(E, idx); const float* ef = &e4.x;
#pragma unroll
                for (int n = 0; n < 4; ++n) rf[n] = 2.f * ef[n] - acc[m][n];
            } else {
#pragma unroll
                for (int n = 0; n < 4; ++n) rf[n] = -acc[m][n];
            }
        } else if (EPI == 3) {
            if (kh == 0) {
                float4 e4 = ld4<ES>(E, idx); const float* ef = &e4.x;
#pragma unroll
                for (int n = 0; n < 4; ++n) rf[n] = ca * ef[n] + cb * acc[m][n];
            } else {
#pragma unroll
                for (int n = 0; n < 4; ++n) rf[n] = cb * acc[m][n];
            }
        } else {   // EPI 4
            if (kh == 0) {
                float4 e4 = ld4<ES>(E, idx); const float* ef = &e4.x;
                float4 f4 = ld4<true>(E2, idx); const float* ff = &f4.x;
#pragma unroll
                for (int n = 0; n < 4; ++n)
                    rf[n] = 2.f * ca * ((u == v0 + tx * 4 + n) ? 1.f : 0.f)
                          + 2.f * cb * ef[n] - ca * ff[n] - cb * acc[m][n];
            } else {
#pragma unroll
                for (int n = 0; n < 4; ++n) rf[n] = -cb * acc[m][n];
            }
        }
        *(float4*)&Dp[idx] = r;
        if (EPI == 1) {                // Gershgorin rowsum (full C, exact)
            float s = fabsf(rf[0]) + fabsf(rf[1]) + fabsf(rf[2]) + fabsf(rf[3]);
            s += __shfl_xor(s, 1); s += __shfl_xor(s, 2);
            s += __shfl_xor(s, 4); s += __shfl_xor(s, 8);
            if (tx == 0) atomicAdd(&scr_w[i * 256 + u], s);
        }
    }
}

// K1: C = B0^T B0 + 2I (unsplit, rowsum) | Bt transpose | Wi transpose-pack
__launch_bounds__(256)
__global__ void k1_fused(const float* __restrict__ B0, const float* __restrict__ W_in,
                         float* __restrict__ C, float* __restrict__ Bt,
                         u16* __restrict__ Wi, float* __restrict__ scr)
{
    const int b = blockIdx.x;
    const int t = threadIdx.x;
    if (b < 128) {
        const int i = b >> 4, tile = b & 15;
        gemm_body<1, 256, false, false, false>(C, B0, B0, nullptr, nullptr,
                                               nullptr, scr, i,
                                               (tile >> 2) * 64, (tile & 3) * 64, 0);
        return;
    }
    __shared__ float tl[32][33];
    const int tx = t & 31, ty = t >> 5;   // 32 x 8
    if (b < 192) {                        // Bt transpose: 64 blocks
        const int bb = b - 128;
        const int i = bb >> 3;
        const size_t off = (size_t)i * 65536;
        const int u0 = (bb & 7) * 32;
        for (int k0 = 0; k0 < 256; k0 += 32) {
            __syncthreads();
#pragma unroll
            for (int r = 0; r < 32; r += 8)
                tl[ty + r][tx] = B0[off + (size_t)(u0 + ty + r) * 256 + k0 + tx];
            __syncthreads();
#pragma unroll
            for (int r = 0; r < 32; r += 8)
                Bt[off + (size_t)(k0 + ty + r) * 256 + u0 + tx] = tl[tx][ty + r];
        }
    } else {                              // Wi pack: 200 blocks
        const int bb = b - 192;           // 25 k-tiles x 8 u-tiles
        const int k0 = (bb % 25) * 32, u0 = (bb / 25) * 32;
#pragma unroll
        for (int r = 0; r < 32; r += 8) {
            const int k = k0 + ty + r;
            tl[ty + r][tx] = (k < 784) ? W_in[(size_t)k * 256 + u0 + tx] : 0.f;
        }
        __syncthreads();
#pragma unroll
        for (int r = 0; r < 32; r += 8)
            Wi[(size_t)(u0 + ty + r) * 800 + k0 + tx] = f2h(tl[tx][ty + r]);
    }
}

// split GEMM dispatch: grid (4,4,16), z = matrix(0..7) + 8*khalf
template<int EPI, bool AS, bool BS, bool ES>
__launch_bounds__(256)
__global__ void gemmS(float* __restrict__ D, const float* __restrict__ A,
                      const float* __restrict__ Bm, const float* __restrict__ E,
                      const float* __restrict__ E2, const float* __restrict__ scr)
{
    const int z = blockIdx.z;
    gemm_body<EPI, 128, AS, BS, ES>(D, A, Bm, E, E2, scr, nullptr,
                                    z & 7, blockIdx.y * 64, blockIdx.x * 64, z >> 3);
}

// P = M Bt (z 0..15) | Q = B M (z 16..31) — one 512-block dispatch
__launch_bounds__(256)
__global__ void gemmPQ(float* __restrict__ P, float* __restrict__ Q,
                       const float* __restrict__ M, const float* __restrict__ Bt)
{
    const int z = blockIdx.z;
    if (z < 16) {
        gemm_body<0, 128, true, false, false>(P, M, Bt, nullptr, nullptr, nullptr,
                nullptr, z & 7, blockIdx.y * 64, blockIdx.x * 64, z >> 3);
    } else {
        const int zz = z - 16;
        gemm_body<0, 128, false, true, false>(Q, Bt, M, nullptr, nullptr, nullptr,
                nullptr, zz & 7, blockIdx.y * 64, blockIdx.x * 64, zz >> 3);
    }
}

// R = B P (z 0..15) | cc (z==16, 8 blocks)
__launch_bounds__(256)
__global__ void gemmRcc(float* __restrict__ R, const float* __restrict__ Bt,
                        const float* __restrict__ P, const float* __restrict__ M,
                        const float* __restrict__ B0, const float* __restrict__ q,
                        float* __restrict__ cc)
{
    const int z = blockIdx.z;
    if (z < 16) {
        gemm_body<0, 128, false, true, false>(R, Bt, P, nullptr, nullptr, nullptr,
                nullptr, z & 7, blockIdx.y * 64, blockIdx.x * 64, z >> 3);
        return;
    }
    if (blockIdx.y != 0 || blockIdx.x >= 8) return;
    __shared__ float qs[256];
    __shared__ float vs[256];
    __shared__ float c1s[256];
    const int i = blockIdx.x;
    const int u = threadIdx.x;
    const size_t ob = (size_t)i * 65536;
    qs[u] = q[i * 256 + u];
    __syncthreads();
    float s0 = 0.f;
    for (int k = 0; k < 256; ++k) s0 += B0[ob + (size_t)k * 256 + u] * qs[k];
    vs[u] = 0.1f * s0;
    __syncthreads();
    float s = 0.f;
    for (int k = 0; k < 256; ++k)
        s += (M[ob + (size_t)k * 256 + u] + M[ob + HS + (size_t)k * 256 + u]) * vs[k];
    c1s[u] = s;
    cc[i * 512 + 256 + u] = s;
    __syncthreads();
    float s2 = 0.f;
    for (int k = 0; k < 256; ++k) s2 += Bt[ob + (size_t)k * 256 + u] * c1s[k];
    cc[i * 512 + u] = 0.1f * qs[u] - s2;
}

// Wc[i][c][512] f16 pack; P,R,Q,M split; all reads row-contiguous
__launch_bounds__(256)
__global__ void pack_wcomb(const float* __restrict__ P, const float* __restrict__ R,
                           const float* __restrict__ Q, const float* __restrict__ M,
                           u16* __restrict__ W)
{
    const int i = blockIdx.y;
    const int e = blockIdx.x * 256 + threadIdx.x;   // 0..262143
    const int c = e >> 9, k = e & 511;
    const size_t off = (size_t)i * 65536;
    float v;
    if (c < 256) {        // z0 row u=c: [I - R | -P^T]
        if (k < 256) {
            const size_t idx = off + (size_t)c * 256 + k;
            v = ((c == k) ? 1.f : 0.f) - (R[idx] + R[idx + HS]);
        } else {
            const size_t idx = off + (size_t)c * 256 + (k - 256);
            v = -(Q[idx] + Q[idx + HS]);
        }
    } else {              // z1 row u=c-256: [P | M]
        const int u = c - 256;
        if (k < 256) {
            const size_t idx = off + (size_t)u * 256 + k;
            v = P[idx] + P[idx + HS];
        } else {
            const size_t idx = off + (size_t)u * 256 + (k - 256);
            v = M[idx] + M[idx + HS];
        }
    }
    W[(size_t)i * 262144 + (size_t)c * 512 + k] = f2h(v);
}

extern "C" void kernel_launch(void* const* d_in, const int* in_sizes, int n_in,
                              void* d_out, int out_size, void* d_ws, size_t ws_size,
                              hipStream_t stream)
{
    const float* x     = (const float*)d_in[0];
    const float* W_in  = (const float*)d_in[1];
    const float* b_in  = (const float*)d_in[2];
    const float* B0    = (const float*)d_in[3];
    const float* q     = (const float*)d_in[4];
    const float* W_out = (const float*)d_in[5];
    const float* b_out = (const float*)d_in[6];

    u16* Wc = (u16*)d_ws;                  // 8 * 262144 u16 = 4 MB
    u16* Wi = Wc + 8 * 262144;             // 256*800 u16
    float* cc = (float*)(Wi + 204800);     // 8*512 floats
    float* F  = cc + 4096;
    float* Bt   = F;                       // 1 slot (plain)
    float* Cm   = F + 1 * HS;              // 1 slot (plain)
    float* bufY = F + 2 * HS;              // 2 slots (split): Y1 / Y2 / R
    float* bufX = F + 4 * HS;              // 2 slots: X1 / P
    float* bufM = F + 6 * HS;              // 2 slots: M
    float* bufQ = F + 8 * HS;              // 2 slots: Q
    float* scr  = F + 10 * HS;             // 2048 floats (rowsums)

    hipMemsetAsync(scr, 0, 2048 * sizeof(float), stream);

    // K1: C = B0^T B0 + 2I (+rowsum) | Bt | Wi
    k1_fused<<<392, 256, 0, stream>>>(B0, W_in, Cm, Bt, Wi, scr);
    // NS iteration 1 with virtual X0 = aI + bC:
    gemmS<3, false, false, false><<<dim3(4, 4, 16), 256, 0, stream>>>(
        bufY, Cm, Cm, Cm, nullptr, scr);                    // Y1 = aC + bC^2
    gemmS<4, false, true, false><<<dim3(4, 4, 16), 256, 0, stream>>>(
        bufX, Cm, bufY, Cm, bufY, scr);                     // X1 = 2X0 - X0*Y1
    // NS iteration 2 (final; rho2 ~ 1e-4 << f16 pack eps):
    gemmS<0, false, true, false><<<dim3(4, 4, 16), 256, 0, stream>>>(
        bufY, Cm, bufX, nullptr, nullptr, nullptr);         // Y2 = C*X1
    gemmS<2, true, true, true><<<dim3(4, 4, 16), 256, 0, stream>>>(
        bufM, bufX, bufY, bufX, nullptr, nullptr);          // M = 2X1 - X1*Y2
    // P = M B^T | Q = B M (one dispatch, 512 blocks):
    gemmPQ<<<dim3(4, 4, 32), 256, 0, stream>>>(bufX, bufQ, bufM, Bt);
    // R = B P | cc:
    gemmRcc<<<dim3(4, 4, 17), 256, 0, stream>>>(bufY, Bt, bufX, bufM, B0, q, cc);
    // pack (P=bufX, R=bufY, Q=bufQ, M=bufM):
    pack_wcomb<<<dim3(1024, 8), 256, 0, stream>>>(bufX, bufY, bufQ, bufM, Wc);

    // ---- the whole network in one kernel ----
    meganet<<<BATCH_N / 128, 1024, 0, stream>>>(
        x, Wi, b_in, Wc, cc, W_out, b_out, (float*)d_out);
}

// Round 7
// 461.734 us; speedup vs baseline: 1.3294x; 1.3294x over previous
//
#include <hip/hip_runtime.h>
#include <cstddef>
#include <cstdint>

#define BATCH_N 32768
#define OUT_DIM 10
#define HS 524288   // split-half offset in floats (8 matrices x 65536)

typedef unsigned short u16;
typedef __attribute__((ext_vector_type(8))) _Float16 half8;
typedef __attribute__((ext_vector_type(4))) float f32x4;

__device__ __forceinline__ u16 f2h(float v) {
    _Float16 h = (_Float16)v;                 // RTN
    return __builtin_bit_cast(u16, h);
}
__device__ __forceinline__ float h2f(u16 h) {
    return (float)__builtin_bit_cast(_Float16, h);
}
__device__ __forceinline__ float tanh_fast(float x) {
    float e = __expf(2.f * x);        // inf -> 1, 0 -> -1 : robust
    return 1.f - 2.f / (e + 1.f);
}

// ============================================================================
// MEGA-FUSED NETWORK KERNEL — R8 structure verbatim (proven 245.8us); only
// the output stage is new: one 16x16x32 MFMA per wave (waves 0..7) replaces
// the ~5100-LDS-instr scalar epilogue.  W_out comes pre-transposed as f16
// WoT[16][256].  The unified VGPR+AGPR budget at 16-wave blocks is 128/wave
// (R10/R12 evidence) — acc[8][2]=64 AGPR + ~64 VGPR fits; do not grow it.
// State [128 x 512] f16 in LDS; A-fragment layout: (m,k) ->
// state[(k>>5)*4096 + (m>>4)*512 + (((k>>3)&3)*16 + (m&15))*8 + (k&7)].
// Weights Wc[layer][c][512] f16, c<256 -> z0 row u=c, c>=256 -> z1 row u=c-256.
// ============================================================================
__global__ __launch_bounds__(1024, 4)
void meganet(const float* __restrict__ X,
             const u16* __restrict__ Wi,        // [256 u][800 k] f16
             const float* __restrict__ b_in,
             const u16* __restrict__ Wc,        // [8][512 c][512 k] f16
             const float* __restrict__ cc,      // [8][512]: [0..255]=c0, [256..511]=c1
             const u16* __restrict__ WoT,       // [16 o][256 k] f16 (W_out^T, padded)
             const float* __restrict__ bo,
             float* __restrict__ out)
{
    __shared__ u16 state[65536];     // 128 KB
    __shared__ float aux[4096];      // 16 KB: x double-buffer
    const int t = threadIdx.x;
    const int wave = t >> 6, lane = t & 63;
    const int fl = lane & 15, kq = lane >> 4;
    const int b0 = blockIdx.x * 128;

    // ---------------- input stage: v0 = x @ W_in + b_in (K=784, pad 800) ----
    f32x4 ai[8];
#pragma unroll
    for (int a = 0; a < 8; ++a) ai[a] = (f32x4){0.f, 0.f, 0.f, 0.f};

    const u16* bpIn = Wi + (size_t)(wave * 16 + fl) * 800 + kq * 8;

    u16* xbuf = (u16*)aux;           // 2 x 4096 u16 chunk buffers
    const int xr = t >> 3;           // row 0..127
    const int xk = (t & 7) * 4;      // 0..28 step 4
    const size_t xrow = (size_t)(b0 + xr) * 784;
    const int xoff = (xr >> 4) * 512 + ((xk >> 3) * 16 + (xr & 15)) * 8 + (xk & 7);

    half8 IB[2];
    float4 xa;
    {   // prologue: chunk0 -> buf0
        float4 x0 = *(const float4*)(X + xrow + xk);
        ushort4 h;
        h.x = f2h(x0.x); h.y = f2h(x0.y); h.z = f2h(x0.z); h.w = f2h(x0.w);
        *(ushort4*)&xbuf[xoff] = h;
        xa = *(const float4*)(X + xrow + 32 + xk);     // chunk 1
        IB[0] = *(const half8*)(bpIn);                 // chunk 0 weights
    }

#pragma unroll
    for (int ki = 0; ki < 25; ++ki) {
        const int cur = ki & 1, nxt = cur ^ 1;
        __syncthreads();                 // buf[cur] ready; buf[nxt] reads done
        if (ki < 24) {                   // stage chunk ki+1 into buf[nxt]
            ushort4 h;
            h.x = f2h(xa.x); h.y = f2h(xa.y); h.z = f2h(xa.z); h.w = f2h(xa.w);
            *(ushort4*)&xbuf[nxt * 4096 + xoff] = h;
            if (ki < 23) {               // load chunk ki+2 (depth-2)
                const int gk = (ki + 2) * 32 + xk;
                const int ga = (gk <= 780) ? gk : 780;   // Wi packs 0 for k>=784
                xa = *(const float4*)(X + xrow + ga);
            }
            IB[nxt] = *(const half8*)(bpIn + (ki + 1) * 32);
        }
        const u16* rb = xbuf + cur * 4096;
#pragma unroll
        for (int mt = 0; mt < 8; ++mt) {
            half8 af = *(const half8*)&rb[mt * 512 + lane * 8];
            ai[mt] = __builtin_amdgcn_mfma_f32_16x16x32_f16(af, IB[cur], ai[mt], 0, 0, 0);
        }
    }

    // layer-0 ks=0 weight prefetch: global, independent of LDS -> issue early
    const u16* bp0 = Wc + (size_t)(wave * 16 + fl) * 512 + kq * 8;   // z0 row u
    const u16* bp1 = bp0 + 131072;                                   // z1 row u
    half8 B[2][2];
    B[0][0] = *(const half8*)(bp0);
    B[0][1] = *(const half8*)(bp1);

    // input epilogue: state v0 (k=u), w = 2*tanh(v0) (k=256+u)
    {
        const float bi = b_in[wave * 16 + fl];
        const int u = wave * 16 + fl;
        const int slab = u >> 5;
        const int cbase = ((u >> 3) & 3) * 128 + (u & 7);
#pragma unroll
        for (int mt = 0; mt < 8; ++mt) {
#pragma unroll
            for (int r = 0; r < 4; ++r) {
                float v = ai[mt][r] + bi;
                float w = 2.f * tanh_fast(v);
                const int base = mt * 512 + (kq * 4 + r) * 8 + cbase;
                state[slab * 4096 + base] = f2h(v);
                state[(8 + slab) * 4096 + base] = f2h(w);
            }
        }
    }

    // ---------------- 8 implicit layers ----------------
    for (int L = 0; L < 8; ++L) {
        const float ccv0 = cc[L * 512 + wave * 16 + fl];
        const float ccv1 = cc[L * 512 + 256 + wave * 16 + fl];
        f32x4 acc[8][2];
#pragma unroll
        for (int a = 0; a < 8; ++a) {
            acc[a][0] = (f32x4){0.f, 0.f, 0.f, 0.f};
            acc[a][1] = (f32x4){0.f, 0.f, 0.f, 0.f};
        }
        __syncthreads();   // state ready
#pragma unroll
        for (int ks = 0; ks < 16; ++ks) {
            const int cur = ks & 1, nxt = cur ^ 1;
            if (ks < 15) {             // prefetch next K-step (2 x 16B)
                B[nxt][0] = *(const half8*)(bp0 + (ks + 1) * 32);
                B[nxt][1] = *(const half8*)(bp1 + (ks + 1) * 32);
            } else {                   // prefetch next layer's ks=0 across epilogue
                bp0 += 262144; bp1 += 262144;
                if (L < 7) {
                    B[nxt][0] = *(const half8*)(bp0);
                    B[nxt][1] = *(const half8*)(bp1);
                }
            }
#pragma unroll
            for (int mt = 0; mt < 8; ++mt) {
                half8 af = *(const half8*)&state[ks * 4096 + mt * 512 + lane * 8];
                acc[mt][0] = __builtin_amdgcn_mfma_f32_16x16x32_f16(af, B[cur][0], acc[mt][0], 0, 0, 0);
                acc[mt][1] = __builtin_amdgcn_mfma_f32_16x16x32_f16(af, B[cur][1], acc[mt][1], 0, 0, 0);
            }
        }
        __syncthreads();   // all state reads done; safe to overwrite
        // epilogue: thread owns z0[u] and z1[u] -> tanh once, no shfl
        {
            const int u = wave * 16 + fl;
            const int slab = u >> 5;
            const int cbase = ((u >> 3) & 3) * 128 + (u & 7);
#pragma unroll
            for (int mt = 0; mt < 8; ++mt) {
#pragma unroll
                for (int r = 0; r < 4; ++r) {
                    float z0 = acc[mt][0][r] + ccv0;
                    float z1 = acc[mt][1][r] + ccv1;
                    float tv = tanh_fast(z0);
                    const int base = mt * 512 + (kq * 4 + r) * 8 + cbase;
                    state[slab * 4096 + base] = f2h(z0);
                    state[(8 + slab) * 4096 + base] = f2h(z1 + tv);
                }
            }
        }
    }

    // ---------------- output stage: out = v0 @ W_out + b_out via MFMA ------
    __syncthreads();
    if (wave < 8) {
        const u16* wp = WoT + fl * 256 + kq * 8;   // B-frag: col=fl, k=kq*8+j
        f32x4 oa = (f32x4){0.f, 0.f, 0.f, 0.f};
#pragma unroll
        for (int ks = 0; ks < 8; ++ks) {           // v0 = state k<256
            half8 af = *(const half8*)&state[ks * 4096 + wave * 512 + lane * 8];
            half8 bf = *(const half8*)(wp + ks * 32);
            oa = __builtin_amdgcn_mfma_f32_16x16x32_f16(af, bf, oa, 0, 0, 0);
        }
        if (fl < 10) {
            const float bv = bo[fl];
#pragma unroll
            for (int r = 0; r < 4; ++r)
                out[(size_t)(b0 + wave * 16 + kq * 4 + r) * 10 + fl] = oa[r] + bv;
        }
    }
}

// ============================================================================
// R13 prep: 3 NS iterations restored (2 iters cost absmax 0.0156->0.0234);
// f16 packing fused into the P/Q/R GEMM epilogues (pack_wcomb dispatch gone,
// Q and R f32 buffers gone).  Chain: memset, k1(+WoT), G1..G6, PQcc, Rpack.
// ============================================================================

template<bool S>
__device__ __forceinline__ float4 ld4(const float* __restrict__ p, size_t idx) {
    float4 v = *(const float4*)(p + idx);
    if constexpr (S) {
        float4 w = *(const float4*)(p + idx + HS);
        v.x += w.x; v.y += w.y; v.z += w.z; v.w += w.w;
    }
    return v;
}

// One 64x64 tile, K-range [kh*KLEN, +KLEN). acc[u][v] = sum_k A[k][u]*B[k][v].
// EPI: 0 D=acc | 1 D=acc+2I & Gershgorin rowsum->scr_w (KLEN=256)
//      2 D=2E-acc (kh0) / -acc (kh1) | 3 D=ca*E+cb*acc | 4 D=2ca I+2cb E-ca E2-cb acc
//      5 D=acc (=P) + pack W z1 rows: [P | M(=E, split)] f16
//      6 no D; pack W z0 right: -acc (= -Q) f16
//      7 no D; pack W z0 left: I - acc (= I-R) f16
template<int EPI, int KLEN, bool AS, bool BS, bool ES>
__device__ __forceinline__ void gemm_body(float* __restrict__ D,
        const float* __restrict__ A, const float* __restrict__ Bm,
        const float* __restrict__ E, const float* __restrict__ E2,
        const float* __restrict__ scr_r, float* __restrict__ scr_w,
        u16* __restrict__ Wp,
        int i, int u0, int v0, int kh)
{
    __shared__ float As[16][64];
    __shared__ float Bs[16][64];
    const size_t off = (size_t)i * 65536;
    const int t  = threadIdx.x;
    const int tx = t & 15, ty = t >> 4;
    const int lk = t >> 4, lv = (t & 15) << 2;

    float ca = 0.f, cb = 0.f;
    if (EPI == 3 || EPI == 4) {        // NS seed coefficients from rowsums
        float* red = &As[0][0];
        red[t] = scr_r[i * 256 + t];
        __syncthreads();
        for (int o = 128; o >= 1; o >>= 1) {
            if (t < o) red[t] = fmaxf(red[t], red[t + o]);
            __syncthreads();
        }
        const float bt_ = red[0];                  // >= lambda_max; lambda_min >= 2
        const float r = (2.f + bt_) * (2.f + bt_) / (8.f * bt_);
        const float e = (r - 1.f) / (r + 1.f);
        cb = -(1.f - e) / (2.f * bt_);
        ca = -cb * (2.f + bt_);
        __syncthreads();
    }

    const int kb = kh * KLEN;
    float acc[4][4];
#pragma unroll
    for (int m = 0; m < 4; ++m)
#pragma unroll
        for (int n = 0; n < 4; ++n) acc[m][n] = 0.f;

    float4 an = ld4<AS>(A, off + (size_t)(kb + lk) * 256 + u0 + lv);
    float4 bn = ld4<BS>(Bm, off + (size_t)(kb + lk) * 256 + v0 + lv);

    for (int k0 = 0; k0 < KLEN; k0 += 16) {
        if (k0) __syncthreads();
        *(float4*)&As[lk][lv] = an;
        *(float4*)&Bs[lk][lv] = bn;
        if (k0 < KLEN - 16) {
            an = ld4<AS>(A, off + (size_t)(kb + k0 + 16 + lk) * 256 + u0 + lv);
            bn = ld4<BS>(Bm, off + (size_t)(kb + k0 + 16 + lk) * 256 + v0 + lv);
        }
        __syncthreads();
#pragma unroll
        for (int kk = 0; kk < 16; ++kk) {
            float af[4], bf[4];
            *(float4*)&af[0] = *(const float4*)&As[kk][ty * 4];
            *(float4*)&bf[0] = *(const float4*)&Bs[kk][tx * 4];
#pragma unroll
            for (int m = 0; m < 4; ++m)
#pragma unroll
                for (int n = 0; n < 4; ++n) acc[m][n] += af[m] * bf[n];
        }
    }

    float* Dp = (EPI <= 5) ? (D + (size_t)kh * HS) : nullptr;
#pragma unroll
    for (int m = 0; m < 4; ++m) {
        const int u = u0 + ty * 4 + m;
        const size_t idx = off + (size_t)u * 256 + v0 + tx * 4;
        float4 r; float* rf = &r.x;
        if (EPI == 0 || EPI == 5) {
#pragma unroll
            for (int n = 0; n < 4; ++n) rf[n] = acc[m][n];
        } else if (EPI == 1) {
#pragma unroll
            for (int n = 0; n < 4; ++n)
                rf[n] = acc[m][n] + ((u == v0 + tx * 4 + n) ? 2.f : 0.f);
        } else if (EPI == 2) {
            if (kh == 0) {
                float4 e4 = ld4<ES>(E, idx); const float* ef = &e4.x;
#pragma unroll
                for (int n = 0; n < 4; ++n) rf[n] = 2.f * ef[n] - acc[m][n];
            } else {
#pragma unroll
                for (int n = 0; n < 4; ++n) rf[n] = -acc[m][n];
            }
        } else if (EPI == 3) {
            if (kh == 0) {
                float4 e4 = ld4<ES>(E, idx); const float* ef = &e4.x;
#pragma unroll
                for (int n = 0; n < 4; ++n) rf[n] = ca * ef[n] + cb * acc[m][n];
            } else {
#pragma unroll
                for (int n = 0; n < 4; ++n) rf[n] = cb * acc[m][n];
            }
        } else if (EPI == 4) {
            if (kh == 0) {
                float4 e4 = ld4<ES>(E, idx); const float* ef = &e4.x;
                float4 f4 = ld4<true>(E2, idx); const float* ff = &f4.x;
#pragma unroll
                for (int n = 0; n < 4; ++n)
                    rf[n] = 2.f * ca * ((u == v0 + tx * 4 + n) ? 1.f : 0.f)
                          + 2.f * cb * ef[n] - ca * ff[n] - cb * acc[m][n];
            } else {
#pragma unroll
                for (int n = 0; n < 4; ++n) rf[n] = -cb * acc[m][n];
            }
        }
        if (EPI <= 5) *(float4*)&Dp[idx] = r;
        if (EPI == 1) {                // Gershgorin rowsum (full C, exact)
            float s = fabsf(rf[0]) + fabsf(rf[1]) + fabsf(rf[2]) + fabsf(rf[3]);
            s += __shfl_xor(s, 1); s += __shfl_xor(s, 2);
            s += __shfl_xor(s, 4); s += __shfl_xor(s, 8);
            if (tx == 0) atomicAdd(&scr_w[i * 256 + u], s);
        }
        if (EPI == 5) {                // pack z1 row 256+u: [P | M]
            u16* wr = Wp + (size_t)i * 262144 + (size_t)(256 + u) * 512;
            ushort4 hp;
            hp.x = f2h(rf[0]); hp.y = f2h(rf[1]); hp.z = f2h(rf[2]); hp.w = f2h(rf[3]);
            *(ushort4*)&wr[v0 + tx * 4] = hp;
            float4 m4 = ld4<true>(E, idx); const float* mf = &m4.x;
            ushort4 hm;
            hm.x = f2h(mf[0]); hm.y = f2h(mf[1]); hm.z = f2h(mf[2]); hm.w = f2h(mf[3]);
            *(ushort4*)&wr[256 + v0 + tx * 4] = hm;
        }
        if (EPI == 6) {                // pack z0 row u, right half: -Q
            u16* wr = Wp + (size_t)i * 262144 + (size_t)u * 512;
            ushort4 hq;
            hq.x = f2h(-acc[m][0]); hq.y = f2h(-acc[m][1]);
            hq.z = f2h(-acc[m][2]); hq.w = f2h(-acc[m][3]);
            *(ushort4*)&wr[256 + v0 + tx * 4] = hq;
        }
        if (EPI == 7) {                // pack z0 row u, left half: I - R
            u16* wr = Wp + (size_t)i * 262144 + (size_t)u * 512;
            ushort4 hr;
            hr.x = f2h(((u == v0 + tx * 4 + 0) ? 1.f : 0.f) - acc[m][0]);
            hr.y = f2h(((u == v0 + tx * 4 + 1) ? 1.f : 0.f) - acc[m][1]);
            hr.z = f2h(((u == v0 + tx * 4 + 2) ? 1.f : 0.f) - acc[m][2]);
            hr.w = f2h(((u == v0 + tx * 4 + 3) ? 1.f : 0.f) - acc[m][3]);
            *(ushort4*)&wr[v0 + tx * 4] = hr;
        }
    }
}

// K1: C = B0^T B0 + 2I (unsplit, rowsum) | Bt transpose | Wi pack | WoT pack
__launch_bounds__(256)
__global__ void k1_fused(const float* __restrict__ B0, const float* __restrict__ W_in,
                         const float* __restrict__ W_out,
                         float* __restrict__ C, float* __restrict__ Bt,
                         u16* __restrict__ Wi, u16* __restrict__ WoT,
                         float* __restrict__ scr)
{
    const int b = blockIdx.x;
    const int t = threadIdx.x;
    if (b < 128) {
        const int i = b >> 4, tile = b & 15;
        gemm_body<1, 256, false, false, false>(C, B0, B0, nullptr, nullptr,
                                               nullptr, scr, nullptr, i,
                                               (tile >> 2) * 64, (tile & 3) * 64, 0);
        return;
    }
    __shared__ float tl[32][33];
    const int tx = t & 31, ty = t >> 5;   // 32 x 8
    if (b < 192) {                        // Bt transpose: 64 blocks
        const int bb = b - 128;
        const int i = bb >> 3;
        const size_t off = (size_t)i * 65536;
        const int u0 = (bb & 7) * 32;
        for (int k0 = 0; k0 < 256; k0 += 32) {
            __syncthreads();
#pragma unroll
            for (int r = 0; r < 32; r += 8)
                tl[ty + r][tx] = B0[off + (size_t)(u0 + ty + r) * 256 + k0 + tx];
            __syncthreads();
#pragma unroll
            for (int r = 0; r < 32; r += 8)
                Bt[off + (size_t)(k0 + ty + r) * 256 + u0 + tx] = tl[tx][ty + r];
        }
    } else if (b < 392) {                 // Wi pack: 200 blocks
        const int bb = b - 192;           // 25 k-tiles x 8 u-tiles
        const int k0 = (bb % 25) * 32, u0 = (bb / 25) * 32;
#pragma unroll
        for (int r = 0; r < 32; r += 8) {
            const int k = k0 + ty + r;
            tl[ty + r][tx] = (k < 784) ? W_in[(size_t)k * 256 + u0 + tx] : 0.f;
        }
        __syncthreads();
#pragma unroll
        for (int r = 0; r < 32; r += 8)
            Wi[(size_t)(u0 + ty + r) * 800 + k0 + tx] = f2h(tl[tx][ty + r]);
    } else {                              // WoT pack: [16 o][256 k]
        for (int idx = t; idx < 4096; idx += 256) {
            const int o = idx >> 8, k = idx & 255;
            WoT[o * 256 + k] = f2h((o < 10) ? W_out[(size_t)k * 10 + o] : 0.f);
        }
    }
}

// split GEMM dispatch: grid (4,4,16), z = matrix(0..7) + 8*khalf
template<int EPI, bool AS, bool BS, bool ES>
__launch_bounds__(256)
__global__ void gemmS(float* __restrict__ D, const float* __restrict__ A,
                      const float* __restrict__ Bm, const float* __restrict__ E,
                      const float* __restrict__ E2, const float* __restrict__ scr)
{
    const int z = blockIdx.z;
    gemm_body<EPI, 128, AS, BS, ES>(D, A, Bm, E, E2, scr, nullptr, nullptr,
                                    z & 7, blockIdx.y * 64, blockIdx.x * 64, z >> 3);
}

// PQcc: z<8: P = M Bt (f32) + pack z1 [P|M] | z 8..15: pack -Q (Q = B M) | z==16: cc
__launch_bounds__(256)
__global__ void gemmPQcc(float* __restrict__ P, const float* __restrict__ M,
                         const float* __restrict__ Bt, const float* __restrict__ B0,
                         const float* __restrict__ q, float* __restrict__ cc,
                         u16* __restrict__ Wc)
{
    const int z = blockIdx.z;
    if (z < 8) {
        gemm_body<5, 256, true, false, true>(P, M, Bt, M, nullptr, nullptr, nullptr,
                Wc, z, blockIdx.y * 64, blockIdx.x * 64, 0);
        return;
    }
    if (z < 16) {
        gemm_body<6, 256, false, true, false>(nullptr, Bt, M, nullptr, nullptr,
                nullptr, nullptr, Wc, z - 8, blockIdx.y * 64, blockIdx.x * 64, 0);
        return;
    }
    if (blockIdx.y != 0 || blockIdx.x >= 8) return;
    __shared__ float qs[256];
    __shared__ float vs[256];
    __shared__ float c1s[256];
    const int i = blockIdx.x;
    const int u = threadIdx.x;
    const size_t ob = (size_t)i * 65536;
    qs[u] = q[i * 256 + u];
    __syncthreads();
    float s0 = 0.f;
    for (int k = 0; k < 256; ++k) s0 += B0[ob + (size_t)k * 256 + u] * qs[k];
    vs[u] = 0.1f * s0;
    __syncthreads();
    float s = 0.f;
    for (int k = 0; k < 256; ++k)
        s += (M[ob + (size_t)k * 256 + u] + M[ob + HS + (size_t)k * 256 + u]) * vs[k];
    c1s[u] = s;
    cc[i * 512 + 256 + u] = s;
    __syncthreads();
    float s2 = 0.f;
    for (int k = 0; k < 256; ++k) s2 += Bt[ob + (size_t)k * 256 + u] * c1s[k];
    cc[i * 512 + u] = 0.1f * qs[u] - s2;
}

// Rpack: R = B P, pack z0 left: I - R (grid (4,4,8))
__launch_bounds__(256)
__global__ void gemmRpack(const float* __restrict__ Bt, const float* __restrict__ P,
                          u16* __restrict__ Wc)
{
    gemm_body<7, 256, false, false, false>(nullptr, Bt, P, nullptr, nullptr,
            nullptr, nullptr, Wc, blockIdx.z, blockIdx.y * 64, blockIdx.x * 64, 0);
}

extern "C" void kernel_launch(void* const* d_in, const int* in_sizes, int n_in,
                              void* d_out, int out_size, void* d_ws, size_t ws_size,
                              hipStream_t stream)
{
    const float* x     = (const float*)d_in[0];
    const float* W_in  = (const float*)d_in[1];
    const float* b_in  = (const float*)d_in[2];
    const float* B0    = (const float*)d_in[3];
    const float* q     = (const float*)d_in[4];
    const float* W_out = (const float*)d_in[5];
    const float* b_out = (const float*)d_in[6];

    u16* Wc  = (u16*)d_ws;                 // 8 * 262144 u16 = 4 MB
    u16* Wi  = Wc + 8 * 262144;            // 256*800 u16
    u16* WoT = Wi + 204800;                // 16*256 u16
    float* cc = (float*)(WoT + 4096);      // 8*512 floats
    float* F  = cc + 4096;
    float* Cm   = F;                       // plain (1 HS)
    float* Bt   = F + 1 * HS;              // plain (1 HS)
    float* bufA = F + 2 * HS;              // split (2 HS): Y1 / X2 / P(plain reuse? no)
    float* bufB = F + 4 * HS;              // split (2 HS): X1 / Y3 / P
    float* bufC = F + 6 * HS;              // split (2 HS): Y2 / M
    float* scr  = F + 8 * HS;              // 2048 floats (rowsums)

    hipMemsetAsync(scr, 0, 2048 * sizeof(float), stream);

    // K1: C = B0^T B0 + 2I (+rowsum) | Bt | Wi | WoT
    k1_fused<<<393, 256, 0, stream>>>(B0, W_in, W_out, Cm, Bt, Wi, WoT, scr);
    // NS iteration 1 with virtual X0 = aI + bC:
    gemmS<3, false, false, false><<<dim3(4, 4, 16), 256, 0, stream>>>(
        bufA, Cm, Cm, Cm, nullptr, scr);                    // Y1 = aC + bC^2
    gemmS<4, false, true, false><<<dim3(4, 4, 16), 256, 0, stream>>>(
        bufB, Cm, bufA, Cm, bufA, scr);                     // X1 = 2X0 - X0*Y1
    // NS iteration 2:
    gemmS<0, false, true, false><<<dim3(4, 4, 16), 256, 0, stream>>>(
        bufC, Cm, bufB, nullptr, nullptr, nullptr);         // Y2 = C*X1
    gemmS<2, true, true, true><<<dim3(4, 4, 16), 256, 0, stream>>>(
        bufA, bufB, bufC, bufB, nullptr, nullptr);          // X2 = 2X1 - X1*Y2
    // NS iteration 3:
    gemmS<0, false, true, false><<<dim3(4, 4, 16), 256, 0, stream>>>(
        bufB, Cm, bufA, nullptr, nullptr, nullptr);         // Y3 = C*X2
    gemmS<2, true, true, true><<<dim3(4, 4, 16), 256, 0, stream>>>(
        bufC, bufA, bufB, bufA, nullptr, nullptr);          // M = 2X2 - X2*Y3
    // P = M B^T (f32, into bufB first half) + pack z1 [P|M] | pack -Q | cc:
    gemmPQcc<<<dim3(4, 4, 17), 256, 0, stream>>>(bufB, bufC, Bt, B0, q, cc, Wc);
    // R = B P, pack z0 [I-R | .]:
    gemmRpack<<<dim3(4, 4, 8), 256, 0, stream>>>(Bt, bufB, Wc);

    // ---- the whole network in one kernel ----
    meganet<<<BATCH_N / 128, 1024, 0, stream>>>(
        x, Wi, b_in, Wc, cc, WoT, b_out, (float*)d_out);
}

// Round 8
// 458.422 us; speedup vs baseline: 1.3390x; 1.0072x over previous
//
#include <hip/hip_runtime.h>
#include <cstddef>
#include <cstdint>

#define BATCH_N 32768
#define OUT_DIM 10
#define HS 524288   // partial-buffer stride in floats (8 matrices x 65536)

typedef unsigned short u16;
typedef __attribute__((ext_vector_type(8))) _Float16 half8;
typedef __attribute__((ext_vector_type(4))) float f32x4;

__device__ __forceinline__ u16 f2h(float v) {
    _Float16 h = (_Float16)v;                 // RTN
    return __builtin_bit_cast(u16, h);
}
__device__ __forceinline__ float h2f(u16 h) {
    return (float)__builtin_bit_cast(_Float16, h);
}
__device__ __forceinline__ float tanh_fast(float x) {
    float e = __expf(2.f * x);        // inf -> 1, 0 -> -1 : robust
    return 1.f - 2.f / (e + 1.f);
}

// ============================================================================
// MEGA-FUSED NETWORK KERNEL — R13 version verbatim (250us control).
// ============================================================================
__global__ __launch_bounds__(1024, 4)
void meganet(const float* __restrict__ X,
             const u16* __restrict__ Wi,        // [256 u][800 k] f16
             const float* __restrict__ b_in,
             const u16* __restrict__ Wc,        // [8][512 c][512 k] f16
             const float* __restrict__ cc,      // [8][512]: [0..255]=c0, [256..511]=c1
             const u16* __restrict__ WoT,       // [16 o][256 k] f16 (W_out^T, padded)
             const float* __restrict__ bo,
             float* __restrict__ out)
{
    __shared__ u16 state[65536];     // 128 KB
    __shared__ float aux[4096];      // 16 KB: x double-buffer
    const int t = threadIdx.x;
    const int wave = t >> 6, lane = t & 63;
    const int fl = lane & 15, kq = lane >> 4;
    const int b0 = blockIdx.x * 128;

    // ---------------- input stage: v0 = x @ W_in + b_in (K=784, pad 800) ----
    f32x4 ai[8];
#pragma unroll
    for (int a = 0; a < 8; ++a) ai[a] = (f32x4){0.f, 0.f, 0.f, 0.f};

    const u16* bpIn = Wi + (size_t)(wave * 16 + fl) * 800 + kq * 8;

    u16* xbuf = (u16*)aux;           // 2 x 4096 u16 chunk buffers
    const int xr = t >> 3;           // row 0..127
    const int xk = (t & 7) * 4;      // 0..28 step 4
    const size_t xrow = (size_t)(b0 + xr) * 784;
    const int xoff = (xr >> 4) * 512 + ((xk >> 3) * 16 + (xr & 15)) * 8 + (xk & 7);

    half8 IB[2];
    float4 xa;
    {   // prologue: chunk0 -> buf0
        float4 x0 = *(const float4*)(X + xrow + xk);
        ushort4 h;
        h.x = f2h(x0.x); h.y = f2h(x0.y); h.z = f2h(x0.z); h.w = f2h(x0.w);
        *(ushort4*)&xbuf[xoff] = h;
        xa = *(const float4*)(X + xrow + 32 + xk);     // chunk 1
        IB[0] = *(const half8*)(bpIn);                 // chunk 0 weights
    }

#pragma unroll
    for (int ki = 0; ki < 25; ++ki) {
        const int cur = ki & 1, nxt = cur ^ 1;
        __syncthreads();                 // buf[cur] ready; buf[nxt] reads done
        if (ki < 24) {                   // stage chunk ki+1 into buf[nxt]
            ushort4 h;
            h.x = f2h(xa.x); h.y = f2h(xa.y); h.z = f2h(xa.z); h.w = f2h(xa.w);
            *(ushort4*)&xbuf[nxt * 4096 + xoff] = h;
            if (ki < 23) {               // load chunk ki+2 (depth-2)
                const int gk = (ki + 2) * 32 + xk;
                const int ga = (gk <= 780) ? gk : 780;   // Wi packs 0 for k>=784
                xa = *(const float4*)(X + xrow + ga);
            }
            IB[nxt] = *(const half8*)(bpIn + (ki + 1) * 32);
        }
        const u16* rb = xbuf + cur * 4096;
#pragma unroll
        for (int mt = 0; mt < 8; ++mt) {
            half8 af = *(const half8*)&rb[mt * 512 + lane * 8];
            ai[mt] = __builtin_amdgcn_mfma_f32_16x16x32_f16(af, IB[cur], ai[mt], 0, 0, 0);
        }
    }

    // layer-0 ks=0 weight prefetch: global, independent of LDS -> issue early
    const u16* bp0 = Wc + (size_t)(wave * 16 + fl) * 512 + kq * 8;   // z0 row u
    const u16* bp1 = bp0 + 131072;                                   // z1 row u
    half8 B[2][2];
    B[0][0] = *(const half8*)(bp0);
    B[0][1] = *(const half8*)(bp1);

    // input epilogue: state v0 (k=u), w = 2*tanh(v0) (k=256+u)
    {
        const float bi = b_in[wave * 16 + fl];
        const int u = wave * 16 + fl;
        const int slab = u >> 5;
        const int cbase = ((u >> 3) & 3) * 128 + (u & 7);
#pragma unroll
        for (int mt = 0; mt < 8; ++mt) {
#pragma unroll
            for (int r = 0; r < 4; ++r) {
                float v = ai[mt][r] + bi;
                float w = 2.f * tanh_fast(v);
                const int base = mt * 512 + (kq * 4 + r) * 8 + cbase;
                state[slab * 4096 + base] = f2h(v);
                state[(8 + slab) * 4096 + base] = f2h(w);
            }
        }
    }

    // ---------------- 8 implicit layers ----------------
    for (int L = 0; L < 8; ++L) {
        const float ccv0 = cc[L * 512 + wave * 16 + fl];
        const float ccv1 = cc[L * 512 + 256 + wave * 16 + fl];
        f32x4 acc[8][2];
#pragma unroll
        for (int a = 0; a < 8; ++a) {
            acc[a][0] = (f32x4){0.f, 0.f, 0.f, 0.f};
            acc[a][1] = (f32x4){0.f, 0.f, 0.f, 0.f};
        }
        __syncthreads();   // state ready
#pragma unroll
        for (int ks = 0; ks < 16; ++ks) {
            const int cur = ks & 1, nxt = cur ^ 1;
            if (ks < 15) {             // prefetch next K-step (2 x 16B)
                B[nxt][0] = *(const half8*)(bp0 + (ks + 1) * 32);
                B[nxt][1] = *(const half8*)(bp1 + (ks + 1) * 32);
            } else {                   // prefetch next layer's ks=0 across epilogue
                bp0 += 262144; bp1 += 262144;
                if (L < 7) {
                    B[nxt][0] = *(const half8*)(bp0);
                    B[nxt][1] = *(const half8*)(bp1);
                }
            }
#pragma unroll
            for (int mt = 0; mt < 8; ++mt) {
                half8 af = *(const half8*)&state[ks * 4096 + mt * 512 + lane * 8];
                acc[mt][0] = __builtin_amdgcn_mfma_f32_16x16x32_f16(af, B[cur][0], acc[mt][0], 0, 0, 0);
                acc[mt][1] = __builtin_amdgcn_mfma_f32_16x16x32_f16(af, B[cur][1], acc[mt][1], 0, 0, 0);
            }
        }
        __syncthreads();   // all state reads done; safe to overwrite
        // epilogue: thread owns z0[u] and z1[u] -> tanh once, no shfl
        {
            const int u = wave * 16 + fl;
            const int slab = u >> 5;
            const int cbase = ((u >> 3) & 3) * 128 + (u & 7);
#pragma unroll
            for (int mt = 0; mt < 8; ++mt) {
#pragma unroll
                for (int r = 0; r < 4; ++r) {
                    float z0 = acc[mt][0][r] + ccv0;
                    float z1 = acc[mt][1][r] + ccv1;
                    float tv = tanh_fast(z0);
                    const int base = mt * 512 + (kq * 4 + r) * 8 + cbase;
                    state[slab * 4096 + base] = f2h(z0);
                    state[(8 + slab) * 4096 + base] = f2h(z1 + tv);
                }
            }
        }
    }

    // ---------------- output stage: out = v0 @ W_out + b_out via MFMA ------
    __syncthreads();
    if (wave < 8) {
        const u16* wp = WoT + fl * 256 + kq * 8;   // B-frag: col=fl, k=kq*8+j
        f32x4 oa = (f32x4){0.f, 0.f, 0.f, 0.f};
#pragma unroll
        for (int ks = 0; ks < 8; ++ks) {           // v0 = state k<256
            half8 af = *(const half8*)&state[ks * 4096 + wave * 512 + lane * 8];
            half8 bf = *(const half8*)(wp + ks * 32);
            oa = __builtin_amdgcn_mfma_f32_16x16x32_f16(af, bf, oa, 0, 0, 0);
        }
        if (fl < 10) {
            const float bv = bo[fl];
#pragma unroll
            for (int r = 0; r < 4; ++r)
                out[(size_t)(b0 + wave * 16 + kq * 4 + r) * 10 + fl] = oa[r] + bv;
        }
    }
}

// ============================================================================
// R14 prep: K-split-4 GEMMs (512 blocks = 2 blocks/CU = 8 waves/CU; R13's 256
// blocks x 4 waves had no latency hiding).  Consumers sum partials in staging.
// Rowsums: per-tile plain stores (4 slots), no atomics, no memset dispatch.
// Chain: k1 -> Y1 -> X1 -> Y2 -> X2 -> Y3 -> M -> PQcc -> R -> pack -> meganet.
// ============================================================================

template<int NS>
__device__ __forceinline__ float4 ldn(const float* __restrict__ p, size_t idx) {
    float4 v = *(const float4*)(p + idx);
#pragma unroll
    for (int s = 1; s < NS; ++s) {
        float4 w = *(const float4*)(p + idx + (size_t)s * HS);
        v.x += w.x; v.y += w.y; v.z += w.z; v.w += w.w;
    }
    return v;
}

// One 64x64 tile, K-range [kh*KLEN, +KLEN). acc[u][v] = sum_k A[k][u]*B[k][v].
// AS/BS/ES/E2S = partial counts of A/B/E/E2.  Output written to D + kh*HS.
// EPI: 0 D=acc
//      1 D=acc+2I, rowsum partial -> scr_w[(i*4 + v0/64)*256 + u]  (KLEN=256)
//      2 D= kh0? 2E-acc : -acc
//      3 D= kh0? ca*E+cb*acc : cb*acc          (NS seed coeffs from scr_r)
//      4 D= kh0? 2ca*I+2cb*E-ca*E2-cb*acc : -cb*acc
template<int EPI, int KLEN, int AS, int BS, int ES, int E2S>
__device__ __forceinline__ void gemm_body(float* __restrict__ D,
        const float* __restrict__ A, const float* __restrict__ Bm,
        const float* __restrict__ E, const float* __restrict__ E2,
        const float* __restrict__ scr_r, float* __restrict__ scr_w,
        int i, int u0, int v0, int kh)
{
    __shared__ float As[16][64];
    __shared__ float Bs[16][64];
    const size_t off = (size_t)i * 65536;
    const int t  = threadIdx.x;
    const int tx = t & 15, ty = t >> 4;
    const int lk = t >> 4, lv = (t & 15) << 2;

    float ca = 0.f, cb = 0.f;
    if (EPI == 3 || EPI == 4) {        // NS seed coefficients from rowsum parts
        float* red = &As[0][0];
        {
            float s = scr_r[i * 1024 + t];
#pragma unroll
            for (int vt = 1; vt < 4; ++vt) s += scr_r[i * 1024 + vt * 256 + t];
            red[t] = s;
        }
        __syncthreads();
        for (int o = 128; o >= 1; o >>= 1) {
            if (t < o) red[t] = fmaxf(red[t], red[t + o]);
            __syncthreads();
        }
        const float bt_ = red[0];                  // >= lambda_max; lambda_min >= 2
        const float r = (2.f + bt_) * (2.f + bt_) / (8.f * bt_);
        const float e = (r - 1.f) / (r + 1.f);
        cb = -(1.f - e) / (2.f * bt_);
        ca = -cb * (2.f + bt_);
        __syncthreads();
    }

    const int kb = kh * KLEN;
    float acc[4][4];
#pragma unroll
    for (int m = 0; m < 4; ++m)
#pragma unroll
        for (int n = 0; n < 4; ++n) acc[m][n] = 0.f;

    float4 an = ldn<AS>(A, off + (size_t)(kb + lk) * 256 + u0 + lv);
    float4 bn = ldn<BS>(Bm, off + (size_t)(kb + lk) * 256 + v0 + lv);

    for (int k0 = 0; k0 < KLEN; k0 += 16) {
        if (k0) __syncthreads();
        *(float4*)&As[lk][lv] = an;
        *(float4*)&Bs[lk][lv] = bn;
        if (k0 < KLEN - 16) {
            an = ldn<AS>(A, off + (size_t)(kb + k0 + 16 + lk) * 256 + u0 + lv);
            bn = ldn<BS>(Bm, off + (size_t)(kb + k0 + 16 + lk) * 256 + v0 + lv);
        }
        __syncthreads();
#pragma unroll
        for (int kk = 0; kk < 16; ++kk) {
            float af[4], bf[4];
            *(float4*)&af[0] = *(const float4*)&As[kk][ty * 4];
            *(float4*)&bf[0] = *(const float4*)&Bs[kk][tx * 4];
#pragma unroll
            for (int m = 0; m < 4; ++m)
#pragma unroll
                for (int n = 0; n < 4; ++n) acc[m][n] += af[m] * bf[n];
        }
    }

    float* Dp = D + (size_t)kh * HS;
#pragma unroll
    for (int m = 0; m < 4; ++m) {
        const int u = u0 + ty * 4 + m;
        const size_t idx = off + (size_t)u * 256 + v0 + tx * 4;
        float4 r; float* rf = &r.x;
        if (EPI == 0) {
#pragma unroll
            for (int n = 0; n < 4; ++n) rf[n] = acc[m][n];
        } else if (EPI == 1) {
#pragma unroll
            for (int n = 0; n < 4; ++n)
                rf[n] = acc[m][n] + ((u == v0 + tx * 4 + n) ? 2.f : 0.f);
        } else if (EPI == 2) {
            if (kh == 0) {
                float4 e4 = ldn<ES>(E, idx); const float* ef = &e4.x;
#pragma unroll
                for (int n = 0; n < 4; ++n) rf[n] = 2.f * ef[n] - acc[m][n];
            } else {
#pragma unroll
                for (int n = 0; n < 4; ++n) rf[n] = -acc[m][n];
            }
        } else if (EPI == 3) {
            if (kh == 0) {
                float4 e4 = ldn<ES>(E, idx); const float* ef = &e4.x;
#pragma unroll
                for (int n = 0; n < 4; ++n) rf[n] = ca * ef[n] + cb * acc[m][n];
            } else {
#pragma unroll
                for (int n = 0; n < 4; ++n) rf[n] = cb * acc[m][n];
            }
        } else {   // EPI 4
            if (kh == 0) {
                float4 e4 = ldn<ES>(E, idx); const float* ef = &e4.x;
                float4 f4 = ldn<E2S>(E2, idx); const float* ff = &f4.x;
#pragma unroll
                for (int n = 0; n < 4; ++n)
                    rf[n] = 2.f * ca * ((u == v0 + tx * 4 + n) ? 1.f : 0.f)
                          + 2.f * cb * ef[n] - ca * ff[n] - cb * acc[m][n];
            } else {
#pragma unroll
                for (int n = 0; n < 4; ++n) rf[n] = -cb * acc[m][n];
            }
        }
        *(float4*)&Dp[idx] = r;
        if (EPI == 1) {                // Gershgorin rowsum partial (plain store)
            float s = fabsf(rf[0]) + fabsf(rf[1]) + fabsf(rf[2]) + fabsf(rf[3]);
            s += __shfl_xor(s, 1); s += __shfl_xor(s, 2);
            s += __shfl_xor(s, 4); s += __shfl_xor(s, 8);
            if (tx == 0) scr_w[(i * 4 + (v0 >> 6)) * 256 + u] = s;
        }
    }
}

// K1: C = B0^T B0 + 2I (unsplit, rowsum parts) | Bt | Wi pack | WoT pack
__launch_bounds__(256)
__global__ void k1_fused(const float* __restrict__ B0, const float* __restrict__ W_in,
                         const float* __restrict__ W_out,
                         float* __restrict__ C, float* __restrict__ Bt,
                         u16* __restrict__ Wi, u16* __restrict__ WoT,
                         float* __restrict__ scr)
{
    const int b = blockIdx.x;
    const int t = threadIdx.x;
    if (b < 128) {
        const int i = b >> 4, tile = b & 15;
        gemm_body<1, 256, 1, 1, 1, 1>(C, B0, B0, nullptr, nullptr,
                                      nullptr, scr, i,
                                      (tile >> 2) * 64, (tile & 3) * 64, 0);
        return;
    }
    __shared__ float tl[32][33];
    const int tx = t & 31, ty = t >> 5;   // 32 x 8
    if (b < 192) {                        // Bt transpose: 64 blocks
        const int bb = b - 128;
        const int i = bb >> 3;
        const size_t off = (size_t)i * 65536;
        const int u0 = (bb & 7) * 32;
        for (int k0 = 0; k0 < 256; k0 += 32) {
            __syncthreads();
#pragma unroll
            for (int r = 0; r < 32; r += 8)
                tl[ty + r][tx] = B0[off + (size_t)(u0 + ty + r) * 256 + k0 + tx];
            __syncthreads();
#pragma unroll
            for (int r = 0; r < 32; r += 8)
                Bt[off + (size_t)(k0 + ty + r) * 256 + u0 + tx] = tl[tx][ty + r];
        }
    } else if (b < 392) {                 // Wi pack: 200 blocks
        const int bb = b - 192;           // 25 k-tiles x 8 u-tiles
        const int k0 = (bb % 25) * 32, u0 = (bb / 25) * 32;
#pragma unroll
        for (int r = 0; r < 32; r += 8) {
            const int k = k0 + ty + r;
            tl[ty + r][tx] = (k < 784) ? W_in[(size_t)k * 256 + u0 + tx] : 0.f;
        }
        __syncthreads();
#pragma unroll
        for (int r = 0; r < 32; r += 8)
            Wi[(size_t)(u0 + ty + r) * 800 + k0 + tx] = f2h(tl[tx][ty + r]);
    } else {                              // WoT pack: [16 o][256 k]
        for (int idx = t; idx < 4096; idx += 256) {
            const int o = idx >> 8, k = idx & 255;
            WoT[o * 256 + k] = f2h((o < 10) ? W_out[(size_t)k * 10 + o] : 0.f);
        }
    }
}

// split GEMM dispatch: grid (4,4,32), z = matrix(0..7) + 8*kq (kq 0..3), K=64
template<int EPI, int AS, int BS, int ES, int E2S>
__launch_bounds__(256)
__global__ void gemmS(float* __restrict__ D, const float* __restrict__ A,
                      const float* __restrict__ Bm, const float* __restrict__ E,
                      const float* __restrict__ E2, const float* __restrict__ scr)
{
    const int z = blockIdx.z;
    gemm_body<EPI, 64, AS, BS, ES, E2S>(D, A, Bm, E, E2, scr, nullptr,
                                        z & 7, blockIdx.y * 64, blockIdx.x * 64,
                                        z >> 3);
}

// PQcc: z<16: P = M Bt (split2) | z 16..31: Q = B M (split2) | z==32: cc
// P -> bufPQ[0..2HS), Q -> bufPQ[2HS..4HS)
__launch_bounds__(256)
__global__ void gemmPQcc(float* __restrict__ bufPQ, const float* __restrict__ M,
                         const float* __restrict__ Bt, const float* __restrict__ B0,
                         const float* __restrict__ q, float* __restrict__ cc)
{
    const int z = blockIdx.z;
    if (z < 16) {
        gemm_body<0, 128, 4, 1, 1, 1>(bufPQ, M, Bt, nullptr, nullptr, nullptr,
                nullptr, z & 7, blockIdx.y * 64, blockIdx.x * 64, (z >> 3) & 1);
        return;
    }
    if (z < 32) {
        const int zz = z - 16;
        gemm_body<0, 128, 1, 4, 1, 1>(bufPQ + 2 * (size_t)HS, Bt, M, nullptr,
                nullptr, nullptr, nullptr, zz & 7,
                blockIdx.y * 64, blockIdx.x * 64, (zz >> 3) & 1);
        return;
    }
    if (blockIdx.y != 0 || blockIdx.x >= 8) return;
    __shared__ float qs[256];
    __shared__ float vs[256];
    __shared__ float c1s[256];
    const int i = blockIdx.x;
    const int u = threadIdx.x;
    const size_t ob = (size_t)i * 65536;
    qs[u] = q[i * 256 + u];
    __syncthreads();
    float s0 = 0.f;
    for (int k = 0; k < 256; ++k) s0 += B0[ob + (size_t)k * 256 + u] * qs[k];
    vs[u] = 0.1f * s0;
    __syncthreads();
    float s = 0.f;
    for (int k = 0; k < 256; ++k) {
        const size_t mi = ob + (size_t)k * 256 + u;
        s += (M[mi] + M[mi + HS] + M[mi + 2 * (size_t)HS] + M[mi + 3 * (size_t)HS]) * vs[k];
    }
    c1s[u] = s;
    cc[i * 512 + 256 + u] = s;
    __syncthreads();
    float s2 = 0.f;
    for (int k = 0; k < 256; ++k) s2 += Bt[ob + (size_t)k * 256 + u] * c1s[k];
    cc[i * 512 + u] = 0.1f * qs[u] - s2;
}

// Wc[i][c][512] f16 pack; sums partials directly (P s2, Q s2, R s4, M s4)
__launch_bounds__(256)
__global__ void pack_wcomb(const float* __restrict__ P, const float* __restrict__ Q,
                           const float* __restrict__ R, const float* __restrict__ M,
                           u16* __restrict__ W)
{
    const int i = blockIdx.y;
    const int e = blockIdx.x * 256 + threadIdx.x;   // 0..262143
    const int c = e >> 9, k = e & 511;
    const size_t off = (size_t)i * 65536;
    float v;
    if (c < 256) {        // z0 row u=c: [I - R | -Q]
        if (k < 256) {
            const size_t idx = off + (size_t)c * 256 + k;
            v = ((c == k) ? 1.f : 0.f)
              - (R[idx] + R[idx + HS] + R[idx + 2 * (size_t)HS] + R[idx + 3 * (size_t)HS]);
        } else {
            const size_t idx = off + (size_t)c * 256 + (k - 256);
            v = -(Q[idx] + Q[idx + HS]);
        }
    } else {              // z1 row u=c-256: [P | M]
        const int u = c - 256;
        if (k < 256) {
            const size_t idx = off + (size_t)u * 256 + k;
            v = P[idx] + P[idx + HS];
        } else {
            const size_t idx = off + (size_t)u * 256 + (k - 256);
            v = M[idx] + M[idx + HS] + M[idx + 2 * (size_t)HS] + M[idx + 3 * (size_t)HS];
        }
    }
    W[(size_t)i * 262144 + (size_t)c * 512 + k] = f2h(v);
}

extern "C" void kernel_launch(void* const* d_in, const int* in_sizes, int n_in,
                              void* d_out, int out_size, void* d_ws, size_t ws_size,
                              hipStream_t stream)
{
    const float* x     = (const float*)d_in[0];
    const float* W_in  = (const float*)d_in[1];
    const float* b_in  = (const float*)d_in[2];
    const float* B0    = (const float*)d_in[3];
    const float* q     = (const float*)d_in[4];
    const float* W_out = (const float*)d_in[5];
    const float* b_out = (const float*)d_in[6];

    u16* Wc  = (u16*)d_ws;                 // 8 * 262144 u16 = 4 MB
    u16* Wi  = Wc + 8 * 262144;            // 256*800 u16
    u16* WoT = Wi + 204800;                // 16*256 u16
    float* cc = (float*)(WoT + 4096);      // 8*512 floats
    float* F  = cc + 4096;
    float* Cm   = F;                       // unsplit (1 HS)
    float* Bt   = F + 1 * HS;              // unsplit (1 HS)
    float* bufY = F + 2 * HS;              // 4 HS: Y1 / Y2 / Y3 / {P,Q}
    float* bufXa = F + 6 * HS;             // 4 HS: X1 / M
    float* bufXb = F + 10 * HS;            // 4 HS: X2 / R
    float* scr  = F + 14 * HS;             // 8192 floats (rowsum partials)

    // K1: C = B0^T B0 + 2I (+rowsum parts) | Bt | Wi | WoT
    k1_fused<<<393, 256, 0, stream>>>(B0, W_in, W_out, Cm, Bt, Wi, WoT, scr);
    // NS iteration 1 with virtual X0 = aI + bC:
    gemmS<3, 1, 1, 1, 1><<<dim3(4, 4, 32), 256, 0, stream>>>(
        bufY, Cm, Cm, Cm, nullptr, scr);                    // Y1 = aC + bC^2
    gemmS<4, 1, 4, 1, 4><<<dim3(4, 4, 32), 256, 0, stream>>>(
        bufXa, Cm, bufY, Cm, bufY, scr);                    // X1 = 2X0 - X0*Y1
    // NS iteration 2:
    gemmS<0, 1, 4, 1, 1><<<dim3(4, 4, 32), 256, 0, stream>>>(
        bufY, Cm, bufXa, nullptr, nullptr, nullptr);        // Y2 = C*X1
    gemmS<2, 4, 4, 4, 1><<<dim3(4, 4, 32), 256, 0, stream>>>(
        bufXb, bufXa, bufY, bufXa, nullptr, nullptr);       // X2 = 2X1 - X1*Y2
    // NS iteration 3:
    gemmS<0, 1, 4, 1, 1><<<dim3(4, 4, 32), 256, 0, stream>>>(
        bufY, Cm, bufXb, nullptr, nullptr, nullptr);        // Y3 = C*X2
    gemmS<2, 4, 4, 4, 1><<<dim3(4, 4, 32), 256, 0, stream>>>(
        bufXa, bufXb, bufY, bufXb, nullptr, nullptr);       // M = 2X2 - X2*Y3
    // P = M B^T (s2) | Q = B M (s2) | cc:
    gemmPQcc<<<dim3(4, 4, 33), 256, 0, stream>>>(bufY, bufXa, Bt, B0, q, cc);
    // R = B P (s4):
    gemmS<0, 1, 2, 1, 1><<<dim3(4, 4, 32), 256, 0, stream>>>(
        bufXb, Bt, bufY, nullptr, nullptr, nullptr);        // R
    // pack (P=bufY, Q=bufY+2HS, R=bufXb, M=bufXa):
    pack_wcomb<<<dim3(1024, 8), 256, 0, stream>>>(
        bufY, bufY + 2 * (size_t)HS, bufXb, bufXa, Wc);

    // ---- the whole network in one kernel ----
    meganet<<<BATCH_N / 128, 1024, 0, stream>>>(
        x, Wi, b_in, Wc, cc, WoT, b_out, (float*)d_out);
}